// Round 12
// baseline (2018.662 us; speedup 1.0000x reference)
//
#include <hip/hip_runtime.h>
#include <stdint.h>

#define N_NODES 50000
#define N_EDGES 12500
#define NNZV    400000
#define STEPS   20
#define DT_F    0.05f
#define SQRTDT_F 0.22360679774997896f

__device__ __forceinline__ float rdlf(float v, int l) {
  return __uint_as_float(__builtin_amdgcn_readlane(__float_as_uint(v), (unsigned)l));
}

// ---------------- threefry2x32 (partitionable layout) ----------------
__device__ __forceinline__ void tf2x32(uint32_t k0, uint32_t k1,
                                       uint32_t x0, uint32_t x1,
                                       uint32_t& o0, uint32_t& o1) {
  uint32_t k2 = k0 ^ k1 ^ 0x1BD11BDAu;
#define TFR(r) { x0 += x1; x1 = (x1 << (r)) | (x1 >> (32 - (r))); x1 ^= x0; }
  x0 += k0; x1 += k1;
  TFR(13) TFR(15) TFR(26) TFR(6)   x0 += k1; x1 += k2 + 1u;
  TFR(17) TFR(29) TFR(16) TFR(24)  x0 += k2; x1 += k0 + 2u;
  TFR(13) TFR(15) TFR(26) TFR(6)   x0 += k0; x1 += k1 + 3u;
  TFR(17) TFR(29) TFR(16) TFR(24)  x0 += k1; x1 += k2 + 4u;
  TFR(13) TFR(15) TFR(26) TFR(6)   x0 += k2; x1 += k0 + 5u;
#undef TFR
  o0 = x0; o1 = x1;
}

// erfinv, XLA polynomial but with hw log: w = -log((1-u)(1+u))
__device__ __forceinline__ float erfinv_fast(float x) {
  float w = -__logf((1.0f - x) * (1.0f + x));
  float p;
  if (w < 5.0f) {
    w = w - 2.5f;
    p =              2.81022636e-08f;
    p = fmaf(p, w,   3.43273939e-07f);
    p = fmaf(p, w,  -3.5233877e-06f);
    p = fmaf(p, w,  -4.39150654e-06f);
    p = fmaf(p, w,   0.00021858087f);
    p = fmaf(p, w,  -0.00125372503f);
    p = fmaf(p, w,  -0.00417768164f);
    p = fmaf(p, w,   0.246640727f);
    p = fmaf(p, w,   1.50140941f);
  } else {
    w = sqrtf(w) - 3.0f;
    p =             -0.000200214257f;
    p = fmaf(p, w,   0.000100950558f);
    p = fmaf(p, w,   0.00134934322f);
    p = fmaf(p, w,  -0.00367342844f);
    p = fmaf(p, w,   0.00573950773f);
    p = fmaf(p, w,  -0.0076224613f);
    p = fmaf(p, w,   0.00943887047f);
    p = fmaf(p, w,   1.00167406f);
    p = fmaf(p, w,   2.83297682f);
  }
  return p * x;
}

__device__ __forceinline__ float bits_to_normal(uint32_t b) {
  float f = __uint_as_float((b >> 9) | 0x3f800000u) - 1.0f;  // [0,1)
  const float lo = -0.99999994f;
  float u = fmaf(f, 2.0f, lo);
  u = fmaxf(u, lo);
  return 1.41421356237f * erfinv_fast(u);
}

// tanh via hw exp: 1 - 2/(e^{2x}+1)
__device__ __forceinline__ float fast_tanhf(float x) {
  float t = __expf(2.0f * x);
  return 1.0f - 2.0f / (t + 1.0f);
}

// ---------------- setup kernels ----------------
__global__ void k_keys(const int* __restrict__ seed, unsigned* __restrict__ keys) {
  int j = threadIdx.x;
  if (j < STEPS) {
    unsigned s = (unsigned)seed[0];
    unsigned o0, o1;
    tf2x32(0u, s, 0u, (unsigned)j, o0, o1);
    keys[2 * j] = o0; keys[2 * j + 1] = o1;
  }
}

__global__ void k_zero(int* __restrict__ p, int n) {
  int i = blockIdx.x * 256 + threadIdx.x;
  if (i < n) p[i] = 0;
}

__global__ void k_hist(const int* __restrict__ nidx, const int* __restrict__ eidx,
                       int* __restrict__ ecnt, int* __restrict__ ncnt) {
  int i = blockIdx.x * 256 + threadIdx.x;
  if (i < NNZV) {
    atomicAdd(&ecnt[eidx[i]], 1);
    atomicAdd(&ncnt[nidx[i]], 1);
  }
}

// ---- hierarchical exclusive scan over cnt[len]: 1024 elems per block ----
__global__ __launch_bounds__(256) void k_reduce(const int* __restrict__ cnt, int len,
                                                int* __restrict__ bsum) {
  __shared__ int sh[256];
  int b = blockIdx.x, tid = threadIdx.x;
  int base = b * 1024 + tid * 4;
  int s = 0;
#pragma unroll
  for (int j = 0; j < 4; ++j) {
    int i = base + j;
    if (i < len) s += cnt[i];
  }
  sh[tid] = s;
  __syncthreads();
  for (int off = 128; off > 0; off >>= 1) {
    if (tid < off) sh[tid] += sh[tid + off];
    __syncthreads();
  }
  if (tid == 0) bsum[b] = sh[0];
}

__global__ __launch_bounds__(256) void k_scanb(int* __restrict__ bsum, int nb) {
  __shared__ int sh[256];
  int tid = threadIdx.x;
  int v = (tid < nb) ? bsum[tid] : 0;
  sh[tid] = v;
  __syncthreads();
  for (int off = 1; off < 256; off <<= 1) {
    int t = (tid >= off) ? sh[tid - off] : 0;
    __syncthreads();
    sh[tid] += t;
    __syncthreads();
  }
  if (tid < nb) bsum[tid] = sh[tid] - v;   // exclusive
}

__global__ __launch_bounds__(256) void k_scatter(const int* __restrict__ cnt,
                                                 const int* __restrict__ bsum, int len,
                                                 int* __restrict__ start,
                                                 int* __restrict__ fill,
                                                 float* __restrict__ dinv) {
  __shared__ int sh[256];
  int b = blockIdx.x, tid = threadIdx.x;
  int base = b * 1024 + tid * 4;
  int c[4], lex[4];
  int s = 0;
#pragma unroll
  for (int j = 0; j < 4; ++j) {
    int i = base + j;
    c[j] = (i < len) ? cnt[i] : 0;
    lex[j] = s;
    s += c[j];
  }
  sh[tid] = s;
  __syncthreads();
  for (int off = 1; off < 256; off <<= 1) {
    int t = (tid >= off) ? sh[tid - off] : 0;
    __syncthreads();
    sh[tid] += t;
    __syncthreads();
  }
  int off0 = bsum[b] + sh[tid] - s;
#pragma unroll
  for (int j = 0; j < 4; ++j) {
    int i = base + j;
    if (i < len) {
      start[i] = off0 + lex[j];
      fill[i] = 0;
      dinv[i] = 1.0f / (float)(c[j] > 1 ? c[j] : 1);
    }
  }
}

__global__ void k_fill(const int* __restrict__ nidx, const int* __restrict__ eidx,
                       const int* __restrict__ estart, const int* __restrict__ nstart,
                       int* __restrict__ efill, int* __restrict__ nfill,
                       int* __restrict__ emem, int* __restrict__ nmem) {
  int i = blockIdx.x * 256 + threadIdx.x;
  if (i < NNZV) {
    int e = eidx[i], n = nidx[i];
    int pe = atomicAdd(&efill[e], 1);
    emem[estart[e] + pe] = n;
    int pn = atomicAdd(&nfill[n], 1);
    nmem[nstart[n] + pn] = e;
  }
}

// stage a 64x64 row-major matrix into LDS, XOR-swizzled (write & read 2-way = free)
__device__ __forceinline__ void stage_swz(const float* __restrict__ w,
                                          float* __restrict__ lds, int tid) {
  for (int idx = tid; idx < 4096; idx += 256) {
    int j = idx >> 6, k = idx & 63;
    lds[k * 64 + (j ^ k)] = w[idx];
  }
}

// ---------------- encoder: y = relu(x@w1^T+b1)@w2^T + b2 ----------------
__global__ __launch_bounds__(256) void k_encoder(
    const float* __restrict__ x, const float* __restrict__ w1,
    const float* __restrict__ b1, const float* __restrict__ w2,
    const float* __restrict__ b2, float* __restrict__ y) {
  __shared__ float lw1[4096], lw2[4096];
  int tid = threadIdx.x;
  stage_swz(w1, lw1, tid);
  stage_swz(w2, lw2, tid);
  __syncthreads();
  int lane = tid & 63, wave = tid >> 6;
  float w1r[64], w2r[64];
#pragma unroll
  for (int k = 0; k < 64; ++k) {
    w1r[k] = lw1[k * 64 + (lane ^ k)];
    w2r[k] = lw2[k * 64 + (lane ^ k)];
  }
  float b1v = b1[lane], b2v = b2[lane];
  int gw = blockIdx.x * 4 + wave, nw = gridDim.x * 4;
  for (int n = gw; n < N_NODES; n += nw) {
    float xv = x[(size_t)n * 64 + lane];
    float a0 = 0.f, a1 = 0.f, a2 = 0.f, a3 = 0.f;
#pragma unroll
    for (int k = 0; k < 64; k += 4) {
      a0 = fmaf(rdlf(xv, k),     w1r[k],     a0);
      a1 = fmaf(rdlf(xv, k + 1), w1r[k + 1], a1);
      a2 = fmaf(rdlf(xv, k + 2), w1r[k + 2], a2);
      a3 = fmaf(rdlf(xv, k + 3), w1r[k + 3], a3);
    }
    float h = fmaxf((a0 + a1) + (a2 + a3) + b1v, 0.f);
    a0 = a1 = a2 = a3 = 0.f;
#pragma unroll
    for (int k = 0; k < 64; k += 4) {
      a0 = fmaf(rdlf(h, k),     w2r[k],     a0);
      a1 = fmaf(rdlf(h, k + 1), w2r[k + 1], a1);
      a2 = fmaf(rdlf(h, k + 2), w2r[k + 2], a2);
      a3 = fmaf(rdlf(h, k + 3), w2r[k + 3], a3);
    }
    y[(size_t)n * 64 + lane] = (a0 + a1) + (a2 + a3) + b2v;
  }
}

// ---------------- per step: edge agg, quarter-wave float4 (4 edges/wave) ----------------
__global__ __launch_bounds__(256) void k_edge(
    const float* __restrict__ y, float* __restrict__ e,
    const int* __restrict__ estart, const int* __restrict__ ecnt,
    const int* __restrict__ emem, const float* __restrict__ edinv,
    const float* __restrict__ cw) {
  __shared__ float lcw[4096];         // W^T, 4-block-preserving XOR swizzle
  __shared__ int   sid[4][4][68];     // staged ids  [wave][q][..] (+pad: quarters on distinct banks)
  __shared__ float xb[4][4][68];      // transposed gather sums
  int tid = threadIdx.x;
  for (int idx = tid; idx < 4096; idx += 256) {
    int f = idx >> 6, k = idx & 63;   // cw[f][k]
    lcw[k * 64 + ((((f >> 2) ^ (k & 15)) << 2) | (f & 3))] = cw[idx];
  }
  __syncthreads();
  int lane = tid & 63, wave = tid >> 6;
  int sub = lane & 15, q = lane >> 4;
  const int NQ = N_EDGES / 4;
  int gw = blockIdx.x * 4 + wave, nw = gridDim.x * 4;
  for (int p = gw; p < NQ; p += nw) {
    int ed = p * 4 + q;
    int st = estart[ed], deg = ecnt[ed];
    float div = edinv[ed];
    int m = max(deg, __shfl_xor(deg, 16));
    m = max(m, __shfl_xor(m, 32));
    float ax = 0.f, ay = 0.f, az = 0.f, aw = 0.f;
    for (int base = 0; base < m; base += 64) {
#pragma unroll
      for (int j = 0; j < 4; ++j) {
        int idx = base + sub + j * 16;
        if (idx < deg) sid[wave][q][sub + j * 16] = emem[st + idx];
      }
      int rem = min(64, m - base);
#pragma unroll 2
      for (int i = 0; i < rem; ++i) {
        int id = sid[wave][q][i];
        if (base + i < deg) {
          const float4 v = *(const float4*)&y[(size_t)id * 64 + sub * 4];
          ax += v.x; ay += v.y; az += v.z; aw += v.w;
        }
      }
    }
    // transpose to LDS, then matvec: out[f'] = sum_k x[k]*W[f'][k]
    float4 a4; a4.x = ax; a4.y = ay; a4.z = az; a4.w = aw;
    *(float4*)&xb[wave][q][sub * 4] = a4;
    float ox = 0.f, oy = 0.f, oz = 0.f, ow = 0.f;
#pragma unroll
    for (int k = 0; k < 64; ++k) {
      float xv = xb[wave][q][k];
      const float4 wv = *(const float4*)&lcw[k * 64 + ((sub ^ (k & 15)) << 2)];
      ox = fmaf(xv, wv.x, ox);
      oy = fmaf(xv, wv.y, oy);
      oz = fmaf(xv, wv.z, oz);
      ow = fmaf(xv, wv.w, ow);
    }
    float4 o4; o4.x = ox * div; o4.y = oy * div; o4.z = oz * div; o4.w = ow * div;
    *(float4*)&e[(size_t)ed * 64 + sub * 4] = o4;
  }
}

// ---------------- per step: node agg + tanh + noise, quarter-wave float4 (4 nodes/wave) ----------------
__global__ __launch_bounds__(256) void k_node(
    const float* __restrict__ e, float* __restrict__ y,
    const int* __restrict__ nstart, const int* __restrict__ ncnt,
    const int* __restrict__ nmem, const float* __restrict__ ndinv,
    const float* __restrict__ cb, const float* __restrict__ sigma,
    const unsigned* __restrict__ keys, int s) {
  __shared__ int sid[4][4][68];
  int tid = threadIdx.x;
  int lane = tid & 63, wave = tid >> 6;
  int sub = lane & 15, q = lane >> 4;
  const float4 cb4 = *(const float4*)&cb[sub * 4];
  float4 sg4 = *(const float4*)&sigma[sub * 4];
  sg4.x *= SQRTDT_F; sg4.y *= SQRTDT_F; sg4.z *= SQRTDT_F; sg4.w *= SQRTDT_F;
  unsigned ka = keys[2 * s], kb = keys[2 * s + 1];
  const int NQ = N_NODES / 4;
  int gw = blockIdx.x * 4 + wave, nw = gridDim.x * 4;
  for (int p = gw; p < NQ; p += nw) {
    int n = p * 4 + q;
    int st = nstart[n], deg = ncnt[n];
    float dinv = ndinv[n];
    float4 yv = *(const float4*)&y[(size_t)n * 64 + sub * 4];
    int m = max(deg, __shfl_xor(deg, 16));
    m = max(m, __shfl_xor(m, 32));
    float ax = 0.f, ay = 0.f, az = 0.f, aw = 0.f;
    for (int base = 0; base < m; base += 64) {
#pragma unroll
      for (int j = 0; j < 4; ++j) {
        int idx = base + sub + j * 16;
        if (idx < deg) sid[wave][q][sub + j * 16] = nmem[st + idx];
      }
      int rem = min(64, m - base);
#pragma unroll 2
      for (int i = 0; i < rem; ++i) {
        int id = sid[wave][q][i];
        if (base + i < deg) {
          const float4 v = *(const float4*)&e[(size_t)id * 64 + sub * 4];
          ax += v.x; ay += v.y; az += v.z; aw += v.w;
        }
      }
    }
    // 4 normals per lane (features sub*4 .. sub*4+3 of node n)
    unsigned c0 = (unsigned)(n * 64 + sub * 4);
    uint32_t r0, r1;
    tf2x32(ka, kb, 0u, c0 + 0u, r0, r1); float d0 = bits_to_normal(r0 ^ r1);
    tf2x32(ka, kb, 0u, c0 + 1u, r0, r1); float d1 = bits_to_normal(r0 ^ r1);
    tf2x32(ka, kb, 0u, c0 + 2u, r0, r1); float d2 = bits_to_normal(r0 ^ r1);
    tf2x32(ka, kb, 0u, c0 + 3u, r0, r1); float d3 = bits_to_normal(r0 ^ r1);
    yv.x = fmaf(fast_tanhf(fmaf(ax, dinv, cb4.x)), DT_F, fmaf(sg4.x, d0, yv.x));
    yv.y = fmaf(fast_tanhf(fmaf(ay, dinv, cb4.y)), DT_F, fmaf(sg4.y, d1, yv.y));
    yv.z = fmaf(fast_tanhf(fmaf(az, dinv, cb4.z)), DT_F, fmaf(sg4.z, d2, yv.z));
    yv.w = fmaf(fast_tanhf(fmaf(aw, dinv, cb4.w)), DT_F, fmaf(sg4.w, d3, yv.w));
    *(float4*)&y[(size_t)n * 64 + sub * 4] = yv;
  }
}

// ---------------- decoder ----------------
__global__ __launch_bounds__(256) void k_decoder(
    const float* __restrict__ y, const float* __restrict__ w1,
    const float* __restrict__ b1, const float* __restrict__ w2,
    const float* __restrict__ b2, float* __restrict__ out) {
  __shared__ float lw1[4096], lw2[4096];
  int tid = threadIdx.x;
  stage_swz(w1, lw1, tid);
  stage_swz(w2, lw2, tid);
  __syncthreads();
  int lane = tid & 63, wave = tid >> 6;
  float w1r[64], w2r[64];
#pragma unroll
  for (int k = 0; k < 64; ++k) {
    w1r[k] = lw1[k * 64 + (lane ^ k)];
    w2r[k] = lw2[k * 64 + (lane ^ k)];
  }
  float b1v = b1[lane], b2v = b2[lane];
  int gw = blockIdx.x * 4 + wave, nw = gridDim.x * 4;
  for (int n = gw; n < N_NODES; n += nw) {
    float xv = y[(size_t)n * 64 + lane];
    float a0 = 0.f, a1 = 0.f, a2 = 0.f, a3 = 0.f;
#pragma unroll
    for (int k = 0; k < 64; k += 4) {
      a0 = fmaf(rdlf(xv, k),     w1r[k],     a0);
      a1 = fmaf(rdlf(xv, k + 1), w1r[k + 1], a1);
      a2 = fmaf(rdlf(xv, k + 2), w1r[k + 2], a2);
      a3 = fmaf(rdlf(xv, k + 3), w1r[k + 3], a3);
    }
    float h = fmaxf((a0 + a1) + (a2 + a3) + b1v, 0.f);
    a0 = a1 = a2 = a3 = 0.f;
#pragma unroll
    for (int k = 0; k < 64; k += 4) {
      a0 = fmaf(rdlf(h, k),     w2r[k],     a0);
      a1 = fmaf(rdlf(h, k + 1), w2r[k + 1], a1);
      a2 = fmaf(rdlf(h, k + 2), w2r[k + 2], a2);
      a3 = fmaf(rdlf(h, k + 3), w2r[k + 3], a3);
    }
    out[(size_t)n * 64 + lane] = (a0 + a1) + (a2 + a3) + b2v;
  }
}

extern "C" void kernel_launch(void* const* d_in, const int* in_sizes, int n_in,
                              void* d_out, int out_size, void* d_ws, size_t ws_size,
                              hipStream_t stream) {
  (void)in_sizes; (void)n_in; (void)out_size; (void)ws_size;
  const float* x      = (const float*)d_in[0];
  const float* enc_w1 = (const float*)d_in[1];
  const float* enc_b1 = (const float*)d_in[2];
  const float* enc_w2 = (const float*)d_in[3];
  const float* enc_b2 = (const float*)d_in[4];
  const float* conv_w = (const float*)d_in[5];
  const float* conv_b = (const float*)d_in[6];
  const float* sigma  = (const float*)d_in[7];
  const float* dec_w1 = (const float*)d_in[8];
  const float* dec_b1 = (const float*)d_in[9];
  const float* dec_w2 = (const float*)d_in[10];
  const float* dec_b2 = (const float*)d_in[11];
  const int* node_idx = (const int*)d_in[12];
  const int* edge_idx = (const int*)d_in[13];
  const int* seed     = (const int*)d_in[14];

  char* wsb = (char*)d_ws;
  size_t off = 0;
  auto alloc = [&](size_t bytes) -> void* {
    void* p = wsb + off;
    off = (off + bytes + 255) & ~(size_t)255;
    return p;
  };
  float* y        = (float*)alloc((size_t)N_NODES * 64 * 4);
  float* e        = (float*)alloc((size_t)N_EDGES * 64 * 4);
  int* edge_cnt   = (int*)alloc((size_t)N_EDGES * 4);
  int* node_cnt   = (int*)alloc((size_t)N_NODES * 4);
  int* edge_start = (int*)alloc((size_t)N_EDGES * 4);
  int* node_start = (int*)alloc((size_t)N_NODES * 4);
  int* edge_fill  = (int*)alloc((size_t)N_EDGES * 4);
  int* node_fill  = (int*)alloc((size_t)N_NODES * 4);
  int* edge_mem   = (int*)alloc((size_t)NNZV * 4 + 64);   // +pad for staged overread safety
  int* node_mem   = (int*)alloc((size_t)NNZV * 4 + 64);
  float* edinv    = (float*)alloc((size_t)N_EDGES * 4);
  float* ndinv    = (float*)alloc((size_t)N_NODES * 4);
  unsigned* keys  = (unsigned*)alloc(2 * STEPS * 4);
  int* ebsum      = (int*)alloc(256 * 4);
  int* nbsum      = (int*)alloc(256 * 4);

  const int EB = (N_EDGES + 1023) / 1024;   // 13
  const int NB = (N_NODES + 1023) / 1024;   // 49

  dim3 b256(256);
  hipLaunchKernelGGL(k_keys, dim3(1), dim3(64), 0, stream, seed, keys);
  hipLaunchKernelGGL(k_zero, dim3((N_EDGES + 255) / 256), b256, 0, stream, edge_cnt, N_EDGES);
  hipLaunchKernelGGL(k_zero, dim3((N_NODES + 255) / 256), b256, 0, stream, node_cnt, N_NODES);
  hipLaunchKernelGGL(k_hist, dim3((NNZV + 255) / 256), b256, 0, stream,
                     node_idx, edge_idx, edge_cnt, node_cnt);
  hipLaunchKernelGGL(k_reduce, dim3(EB), b256, 0, stream, edge_cnt, N_EDGES, ebsum);
  hipLaunchKernelGGL(k_reduce, dim3(NB), b256, 0, stream, node_cnt, N_NODES, nbsum);
  hipLaunchKernelGGL(k_scanb, dim3(1), b256, 0, stream, ebsum, EB);
  hipLaunchKernelGGL(k_scanb, dim3(1), b256, 0, stream, nbsum, NB);
  hipLaunchKernelGGL(k_scatter, dim3(EB), b256, 0, stream,
                     edge_cnt, ebsum, N_EDGES, edge_start, edge_fill, edinv);
  hipLaunchKernelGGL(k_scatter, dim3(NB), b256, 0, stream,
                     node_cnt, nbsum, N_NODES, node_start, node_fill, ndinv);
  hipLaunchKernelGGL(k_fill, dim3((NNZV + 255) / 256), b256, 0, stream,
                     node_idx, edge_idx, edge_start, node_start,
                     edge_fill, node_fill, edge_mem, node_mem);
  hipLaunchKernelGGL(k_encoder, dim3(1024), b256, 0, stream,
                     x, enc_w1, enc_b1, enc_w2, enc_b2, y);
  for (int s = 0; s < STEPS; ++s) {
    hipLaunchKernelGGL(k_edge, dim3(782), b256, 0, stream,
                       y, e, edge_start, edge_cnt, edge_mem, edinv, conv_w);
    hipLaunchKernelGGL(k_node, dim3(3125), b256, 0, stream,
                       e, y, node_start, node_cnt, node_mem, ndinv,
                       conv_b, sigma, keys, s);
  }
  hipLaunchKernelGGL(k_decoder, dim3(1024), b256, 0, stream,
                     y, dec_w1, dec_b1, dec_w2, dec_b2, (float*)d_out);
}

// Round 13
// 1201.666 us; speedup vs baseline: 1.6799x; 1.6799x over previous
//
#include <hip/hip_runtime.h>
#include <stdint.h>

#define N_NODES 50000
#define N_EDGES 12500
#define NNZV    400000
#define STEPS   20
#define DT_F    0.05f
#define SQRTDT_F 0.22360679774997896f

__device__ __forceinline__ float rdlf(float v, int l) {
  return __uint_as_float(__builtin_amdgcn_readlane(__float_as_uint(v), (unsigned)l));
}
__device__ __forceinline__ int rfl(int v) {
  return (int)__builtin_amdgcn_readfirstlane((unsigned)v);
}

// ---------------- threefry2x32 (partitionable layout) ----------------
__device__ __forceinline__ void tf2x32(uint32_t k0, uint32_t k1,
                                       uint32_t x0, uint32_t x1,
                                       uint32_t& o0, uint32_t& o1) {
  uint32_t k2 = k0 ^ k1 ^ 0x1BD11BDAu;
#define TFR(r) { x0 += x1; x1 = (x1 << (r)) | (x1 >> (32 - (r))); x1 ^= x0; }
  x0 += k0; x1 += k1;
  TFR(13) TFR(15) TFR(26) TFR(6)   x0 += k1; x1 += k2 + 1u;
  TFR(17) TFR(29) TFR(16) TFR(24)  x0 += k2; x1 += k0 + 2u;
  TFR(13) TFR(15) TFR(26) TFR(6)   x0 += k0; x1 += k1 + 3u;
  TFR(17) TFR(29) TFR(16) TFR(24)  x0 += k1; x1 += k2 + 4u;
  TFR(13) TFR(15) TFR(26) TFR(6)   x0 += k2; x1 += k0 + 5u;
#undef TFR
  o0 = x0; o1 = x1;
}

// erfinv, XLA polynomial but with hw log: w = -log((1-u)(1+u))
__device__ __forceinline__ float erfinv_fast(float x) {
  float w = -__logf((1.0f - x) * (1.0f + x));
  float p;
  if (w < 5.0f) {
    w = w - 2.5f;
    p =              2.81022636e-08f;
    p = fmaf(p, w,   3.43273939e-07f);
    p = fmaf(p, w,  -3.5233877e-06f);
    p = fmaf(p, w,  -4.39150654e-06f);
    p = fmaf(p, w,   0.00021858087f);
    p = fmaf(p, w,  -0.00125372503f);
    p = fmaf(p, w,  -0.00417768164f);
    p = fmaf(p, w,   0.246640727f);
    p = fmaf(p, w,   1.50140941f);
  } else {
    w = sqrtf(w) - 3.0f;
    p =             -0.000200214257f;
    p = fmaf(p, w,   0.000100950558f);
    p = fmaf(p, w,   0.00134934322f);
    p = fmaf(p, w,  -0.00367342844f);
    p = fmaf(p, w,   0.00573950773f);
    p = fmaf(p, w,  -0.0076224613f);
    p = fmaf(p, w,   0.00943887047f);
    p = fmaf(p, w,   1.00167406f);
    p = fmaf(p, w,   2.83297682f);
  }
  return p * x;
}

__device__ __forceinline__ float bits_to_normal(uint32_t b) {
  float f = __uint_as_float((b >> 9) | 0x3f800000u) - 1.0f;  // [0,1)
  const float lo = -0.99999994f;
  float u = fmaf(f, 2.0f, lo);
  u = fmaxf(u, lo);
  return 1.41421356237f * erfinv_fast(u);
}

// tanh via hw exp: 1 - 2/(e^{2x}+1)
__device__ __forceinline__ float fast_tanhf(float x) {
  float t = __expf(2.0f * x);
  return 1.0f - 2.0f / (t + 1.0f);
}

// ---------------- setup kernels ----------------
__global__ void k_keys(const int* __restrict__ seed, unsigned* __restrict__ keys) {
  int j = threadIdx.x;
  if (j < STEPS) {
    unsigned s = (unsigned)seed[0];
    unsigned o0, o1;
    tf2x32(0u, s, 0u, (unsigned)j, o0, o1);
    keys[2 * j] = o0; keys[2 * j + 1] = o1;
  }
}

__global__ void k_zero(int* __restrict__ p, int n) {
  int i = blockIdx.x * 256 + threadIdx.x;
  if (i < n) p[i] = 0;
}

__global__ void k_hist(const int* __restrict__ nidx, const int* __restrict__ eidx,
                       int* __restrict__ ecnt, int* __restrict__ ncnt) {
  int i = blockIdx.x * 256 + threadIdx.x;
  if (i < NNZV) {
    atomicAdd(&ecnt[eidx[i]], 1);
    atomicAdd(&ncnt[nidx[i]], 1);
  }
}

// ---- hierarchical exclusive scan over cnt[len]: 1024 elems per block ----
__global__ __launch_bounds__(256) void k_reduce(const int* __restrict__ cnt, int len,
                                                int* __restrict__ bsum) {
  __shared__ int sh[256];
  int b = blockIdx.x, tid = threadIdx.x;
  int base = b * 1024 + tid * 4;
  int s = 0;
#pragma unroll
  for (int j = 0; j < 4; ++j) {
    int i = base + j;
    if (i < len) s += cnt[i];
  }
  sh[tid] = s;
  __syncthreads();
  for (int off = 128; off > 0; off >>= 1) {
    if (tid < off) sh[tid] += sh[tid + off];
    __syncthreads();
  }
  if (tid == 0) bsum[b] = sh[0];
}

__global__ __launch_bounds__(256) void k_scanb(int* __restrict__ bsum, int nb) {
  __shared__ int sh[256];
  int tid = threadIdx.x;
  int v = (tid < nb) ? bsum[tid] : 0;
  sh[tid] = v;
  __syncthreads();
  for (int off = 1; off < 256; off <<= 1) {
    int t = (tid >= off) ? sh[tid - off] : 0;
    __syncthreads();
    sh[tid] += t;
    __syncthreads();
  }
  if (tid < nb) bsum[tid] = sh[tid] - v;   // exclusive
}

__global__ __launch_bounds__(256) void k_scatter(const int* __restrict__ cnt,
                                                 const int* __restrict__ bsum, int len,
                                                 int* __restrict__ start,
                                                 int* __restrict__ fill,
                                                 float* __restrict__ dinv) {
  __shared__ int sh[256];
  int b = blockIdx.x, tid = threadIdx.x;
  int base = b * 1024 + tid * 4;
  int c[4], lex[4];
  int s = 0;
#pragma unroll
  for (int j = 0; j < 4; ++j) {
    int i = base + j;
    c[j] = (i < len) ? cnt[i] : 0;
    lex[j] = s;
    s += c[j];
  }
  sh[tid] = s;
  __syncthreads();
  for (int off = 1; off < 256; off <<= 1) {
    int t = (tid >= off) ? sh[tid - off] : 0;
    __syncthreads();
    sh[tid] += t;
    __syncthreads();
  }
  int off0 = bsum[b] + sh[tid] - s;
#pragma unroll
  for (int j = 0; j < 4; ++j) {
    int i = base + j;
    if (i < len) {
      start[i] = off0 + lex[j];
      fill[i] = 0;
      dinv[i] = 1.0f / (float)(c[j] > 1 ? c[j] : 1);
    }
  }
}

__global__ void k_fill(const int* __restrict__ nidx, const int* __restrict__ eidx,
                       const int* __restrict__ estart, const int* __restrict__ nstart,
                       int* __restrict__ efill, int* __restrict__ nfill,
                       int* __restrict__ emem, int* __restrict__ nmem) {
  int i = blockIdx.x * 256 + threadIdx.x;
  if (i < NNZV) {
    int e = eidx[i], n = nidx[i];
    int pe = atomicAdd(&efill[e], 1);
    emem[estart[e] + pe] = n;
    int pn = atomicAdd(&nfill[n], 1);
    nmem[nstart[n] + pn] = e;
  }
}

// stage a 64x64 row-major matrix into LDS, XOR-swizzled (write & read 2-way = free)
__device__ __forceinline__ void stage_swz(const float* __restrict__ w,
                                          float* __restrict__ lds, int tid) {
  for (int idx = tid; idx < 4096; idx += 256) {
    int j = idx >> 6, k = idx & 63;
    lds[k * 64 + (j ^ k)] = w[idx];
  }
}

// scalar-uniform gather-sum: segment ids loaded via uniform (SGPR) loads,
// row loads use scalar base + lane offset. Up to 16 row loads in flight.
__device__ __forceinline__ float seg_gather_scalar(const float* __restrict__ rows,
                                                   const int* __restrict__ mem,
                                                   int st, int deg, int lane) {
  float a0 = 0.f, a1 = 0.f, a2 = 0.f, a3 = 0.f;
  int i = 0;
  for (; i + 16 <= deg; i += 16) {
    int d0 = mem[st + i],      d1 = mem[st + i + 1];
    int d2 = mem[st + i + 2],  d3 = mem[st + i + 3];
    int d4 = mem[st + i + 4],  d5 = mem[st + i + 5];
    int d6 = mem[st + i + 6],  d7 = mem[st + i + 7];
    int d8 = mem[st + i + 8],  d9 = mem[st + i + 9];
    int da = mem[st + i + 10], db = mem[st + i + 11];
    int dc = mem[st + i + 12], dd = mem[st + i + 13];
    int de = mem[st + i + 14], df = mem[st + i + 15];
    float v0 = rows[(size_t)d0 * 64 + lane], v1 = rows[(size_t)d1 * 64 + lane];
    float v2 = rows[(size_t)d2 * 64 + lane], v3 = rows[(size_t)d3 * 64 + lane];
    float v4 = rows[(size_t)d4 * 64 + lane], v5 = rows[(size_t)d5 * 64 + lane];
    float v6 = rows[(size_t)d6 * 64 + lane], v7 = rows[(size_t)d7 * 64 + lane];
    float v8 = rows[(size_t)d8 * 64 + lane], v9 = rows[(size_t)d9 * 64 + lane];
    float va = rows[(size_t)da * 64 + lane], vb = rows[(size_t)db * 64 + lane];
    float vc = rows[(size_t)dc * 64 + lane], vd = rows[(size_t)dd * 64 + lane];
    float ve = rows[(size_t)de * 64 + lane], vf = rows[(size_t)df * 64 + lane];
    a0 += (v0 + v1) + (v2 + v3);
    a1 += (v4 + v5) + (v6 + v7);
    a2 += (v8 + v9) + (va + vb);
    a3 += (vc + vd) + (ve + vf);
  }
  for (; i + 8 <= deg; i += 8) {
    int d0 = mem[st + i],     d1 = mem[st + i + 1];
    int d2 = mem[st + i + 2], d3 = mem[st + i + 3];
    int d4 = mem[st + i + 4], d5 = mem[st + i + 5];
    int d6 = mem[st + i + 6], d7 = mem[st + i + 7];
    float v0 = rows[(size_t)d0 * 64 + lane], v1 = rows[(size_t)d1 * 64 + lane];
    float v2 = rows[(size_t)d2 * 64 + lane], v3 = rows[(size_t)d3 * 64 + lane];
    float v4 = rows[(size_t)d4 * 64 + lane], v5 = rows[(size_t)d5 * 64 + lane];
    float v6 = rows[(size_t)d6 * 64 + lane], v7 = rows[(size_t)d7 * 64 + lane];
    a0 += (v0 + v1) + (v2 + v3);
    a1 += (v4 + v5) + (v6 + v7);
  }
  for (; i < deg; ++i)
    a0 += rows[(size_t)mem[st + i] * 64 + lane];
  return (a0 + a1) + (a2 + a3);
}

// ---------------- encoder: y = relu(x@w1^T+b1)@w2^T + b2 ----------------
__global__ __launch_bounds__(256) void k_encoder(
    const float* __restrict__ x, const float* __restrict__ w1,
    const float* __restrict__ b1, const float* __restrict__ w2,
    const float* __restrict__ b2, float* __restrict__ y) {
  __shared__ float lw1[4096], lw2[4096];
  int tid = threadIdx.x;
  stage_swz(w1, lw1, tid);
  stage_swz(w2, lw2, tid);
  __syncthreads();
  int lane = tid & 63, wave = tid >> 6;
  float w1r[64], w2r[64];
#pragma unroll
  for (int k = 0; k < 64; ++k) {
    w1r[k] = lw1[k * 64 + (lane ^ k)];
    w2r[k] = lw2[k * 64 + (lane ^ k)];
  }
  float b1v = b1[lane], b2v = b2[lane];
  int gw = blockIdx.x * 4 + wave, nw = gridDim.x * 4;
  for (int n = gw; n < N_NODES; n += nw) {
    float xv = x[(size_t)n * 64 + lane];
    float a0 = 0.f, a1 = 0.f, a2 = 0.f, a3 = 0.f;
#pragma unroll
    for (int k = 0; k < 64; k += 4) {
      a0 = fmaf(rdlf(xv, k),     w1r[k],     a0);
      a1 = fmaf(rdlf(xv, k + 1), w1r[k + 1], a1);
      a2 = fmaf(rdlf(xv, k + 2), w1r[k + 2], a2);
      a3 = fmaf(rdlf(xv, k + 3), w1r[k + 3], a3);
    }
    float h = fmaxf((a0 + a1) + (a2 + a3) + b1v, 0.f);
    a0 = a1 = a2 = a3 = 0.f;
#pragma unroll
    for (int k = 0; k < 64; k += 4) {
      a0 = fmaf(rdlf(h, k),     w2r[k],     a0);
      a1 = fmaf(rdlf(h, k + 1), w2r[k + 1], a1);
      a2 = fmaf(rdlf(h, k + 2), w2r[k + 2], a2);
      a3 = fmaf(rdlf(h, k + 3), w2r[k + 3], a3);
    }
    y[(size_t)n * 64 + lane] = (a0 + a1) + (a2 + a3) + b2v;
  }
}

// ---------------- per step: edge aggregation + per-EDGE matvec ----------------
__global__ __launch_bounds__(256) void k_edge(
    const float* __restrict__ y, float* __restrict__ e,
    const int* __restrict__ estart, const int* __restrict__ ecnt,
    const int* __restrict__ emem, const float* __restrict__ edinv,
    const float* __restrict__ cw) {
  __shared__ float lcw[4096];
  int tid = threadIdx.x;
  stage_swz(cw, lcw, tid);
  __syncthreads();
  int lane = tid & 63, wave = tid >> 6;
  int gw = blockIdx.x * 4 + wave, nw = gridDim.x * 4;
  for (int ed = gw; ed < N_EDGES; ed += nw) {
    int edu = rfl(ed);                       // wave-uniform -> scalar loads below
    int st  = estart[edu], deg = ecnt[edu];
    float div = edinv[edu];
    float acc = seg_gather_scalar(y, emem, st, deg, lane);
    float a0 = 0.f, a1 = 0.f, a2 = 0.f, a3 = 0.f;
#pragma unroll
    for (int k = 0; k < 64; k += 4) {
      a0 = fmaf(rdlf(acc, k),     lcw[k * 64 + (lane ^ k)],             a0);
      a1 = fmaf(rdlf(acc, k + 1), lcw[(k + 1) * 64 + (lane ^ (k + 1))], a1);
      a2 = fmaf(rdlf(acc, k + 2), lcw[(k + 2) * 64 + (lane ^ (k + 2))], a2);
      a3 = fmaf(rdlf(acc, k + 3), lcw[(k + 3) * 64 + (lane ^ (k + 3))], a3);
    }
    e[(size_t)edu * 64 + lane] = ((a0 + a1) + (a2 + a3)) * div;
  }
}

// ---------------- per step: node aggregation + tanh + noise + y update ----------------
__global__ __launch_bounds__(256) void k_node(
    const float* __restrict__ e, float* __restrict__ y,
    const int* __restrict__ nstart, const int* __restrict__ ncnt,
    const int* __restrict__ nmem, const float* __restrict__ ndinv,
    const float* __restrict__ cb, const float* __restrict__ sigma,
    const unsigned* __restrict__ keys, int s) {
  int tid = threadIdx.x;
  int lane = tid & 63, wave = tid >> 6;
  float cbv = cb[lane];
  float sgv = sigma[lane] * SQRTDT_F;
  unsigned ka = keys[2 * s], kb = keys[2 * s + 1];
  int gw = blockIdx.x * 4 + wave, nw = gridDim.x * 4;
  for (int n = gw; n < N_NODES; n += nw) {
    int nu = rfl(n);                         // wave-uniform -> scalar loads below
    int st = nstart[nu], deg = ncnt[nu];
    float dinv = ndinv[nu];
    float yv = y[(size_t)nu * 64 + lane];    // independent load, issued early
    float acc = seg_gather_scalar(e, nmem, st, deg, lane);
    uint32_t r0, r1;
    tf2x32(ka, kb, 0u, (unsigned)(nu * 64 + lane), r0, r1);
    float dw = bits_to_normal(r0 ^ r1);
    yv = fmaf(fast_tanhf(fmaf(acc, dinv, cbv)), DT_F, fmaf(sgv, dw, yv));
    y[(size_t)nu * 64 + lane] = yv;
  }
}

// ---------------- decoder ----------------
__global__ __launch_bounds__(256) void k_decoder(
    const float* __restrict__ y, const float* __restrict__ w1,
    const float* __restrict__ b1, const float* __restrict__ w2,
    const float* __restrict__ b2, float* __restrict__ out) {
  __shared__ float lw1[4096], lw2[4096];
  int tid = threadIdx.x;
  stage_swz(w1, lw1, tid);
  stage_swz(w2, lw2, tid);
  __syncthreads();
  int lane = tid & 63, wave = tid >> 6;
  float w1r[64], w2r[64];
#pragma unroll
  for (int k = 0; k < 64; ++k) {
    w1r[k] = lw1[k * 64 + (lane ^ k)];
    w2r[k] = lw2[k * 64 + (lane ^ k)];
  }
  float b1v = b1[lane], b2v = b2[lane];
  int gw = blockIdx.x * 4 + wave, nw = gridDim.x * 4;
  for (int n = gw; n < N_NODES; n += nw) {
    float xv = y[(size_t)n * 64 + lane];
    float a0 = 0.f, a1 = 0.f, a2 = 0.f, a3 = 0.f;
#pragma unroll
    for (int k = 0; k < 64; k += 4) {
      a0 = fmaf(rdlf(xv, k),     w1r[k],     a0);
      a1 = fmaf(rdlf(xv, k + 1), w1r[k + 1], a1);
      a2 = fmaf(rdlf(xv, k + 2), w1r[k + 2], a2);
      a3 = fmaf(rdlf(xv, k + 3), w1r[k + 3], a3);
    }
    float h = fmaxf((a0 + a1) + (a2 + a3) + b1v, 0.f);
    a0 = a1 = a2 = a3 = 0.f;
#pragma unroll
    for (int k = 0; k < 64; k += 4) {
      a0 = fmaf(rdlf(h, k),     w2r[k],     a0);
      a1 = fmaf(rdlf(h, k + 1), w2r[k + 1], a1);
      a2 = fmaf(rdlf(h, k + 2), w2r[k + 2], a2);
      a3 = fmaf(rdlf(h, k + 3), w2r[k + 3], a3);
    }
    out[(size_t)n * 64 + lane] = (a0 + a1) + (a2 + a3) + b2v;
  }
}

extern "C" void kernel_launch(void* const* d_in, const int* in_sizes, int n_in,
                              void* d_out, int out_size, void* d_ws, size_t ws_size,
                              hipStream_t stream) {
  (void)in_sizes; (void)n_in; (void)out_size; (void)ws_size;
  const float* x      = (const float*)d_in[0];
  const float* enc_w1 = (const float*)d_in[1];
  const float* enc_b1 = (const float*)d_in[2];
  const float* enc_w2 = (const float*)d_in[3];
  const float* enc_b2 = (const float*)d_in[4];
  const float* conv_w = (const float*)d_in[5];
  const float* conv_b = (const float*)d_in[6];
  const float* sigma  = (const float*)d_in[7];
  const float* dec_w1 = (const float*)d_in[8];
  const float* dec_b1 = (const float*)d_in[9];
  const float* dec_w2 = (const float*)d_in[10];
  const float* dec_b2 = (const float*)d_in[11];
  const int* node_idx = (const int*)d_in[12];
  const int* edge_idx = (const int*)d_in[13];
  const int* seed     = (const int*)d_in[14];

  char* wsb = (char*)d_ws;
  size_t off = 0;
  auto alloc = [&](size_t bytes) -> void* {
    void* p = wsb + off;
    off = (off + bytes + 255) & ~(size_t)255;
    return p;
  };
  float* y        = (float*)alloc((size_t)N_NODES * 64 * 4);
  float* e        = (float*)alloc((size_t)N_EDGES * 64 * 4);
  int* edge_cnt   = (int*)alloc((size_t)N_EDGES * 4);
  int* node_cnt   = (int*)alloc((size_t)N_NODES * 4);
  int* edge_start = (int*)alloc((size_t)N_EDGES * 4);
  int* node_start = (int*)alloc((size_t)N_NODES * 4);
  int* edge_fill  = (int*)alloc((size_t)N_EDGES * 4);
  int* node_fill  = (int*)alloc((size_t)N_NODES * 4);
  int* edge_mem   = (int*)alloc((size_t)NNZV * 4);
  int* node_mem   = (int*)alloc((size_t)NNZV * 4);
  float* edinv    = (float*)alloc((size_t)N_EDGES * 4);
  float* ndinv    = (float*)alloc((size_t)N_NODES * 4);
  unsigned* keys  = (unsigned*)alloc(2 * STEPS * 4);
  int* ebsum      = (int*)alloc(256 * 4);
  int* nbsum      = (int*)alloc(256 * 4);

  const int EB = (N_EDGES + 1023) / 1024;   // 13
  const int NB = (N_NODES + 1023) / 1024;   // 49

  dim3 b256(256);
  hipLaunchKernelGGL(k_keys, dim3(1), dim3(64), 0, stream, seed, keys);
  hipLaunchKernelGGL(k_zero, dim3((N_EDGES + 255) / 256), b256, 0, stream, edge_cnt, N_EDGES);
  hipLaunchKernelGGL(k_zero, dim3((N_NODES + 255) / 256), b256, 0, stream, node_cnt, N_NODES);
  hipLaunchKernelGGL(k_hist, dim3((NNZV + 255) / 256), b256, 0, stream,
                     node_idx, edge_idx, edge_cnt, node_cnt);
  hipLaunchKernelGGL(k_reduce, dim3(EB), b256, 0, stream, edge_cnt, N_EDGES, ebsum);
  hipLaunchKernelGGL(k_reduce, dim3(NB), b256, 0, stream, node_cnt, N_NODES, nbsum);
  hipLaunchKernelGGL(k_scanb, dim3(1), b256, 0, stream, ebsum, EB);
  hipLaunchKernelGGL(k_scanb, dim3(1), b256, 0, stream, nbsum, NB);
  hipLaunchKernelGGL(k_scatter, dim3(EB), b256, 0, stream,
                     edge_cnt, ebsum, N_EDGES, edge_start, edge_fill, edinv);
  hipLaunchKernelGGL(k_scatter, dim3(NB), b256, 0, stream,
                     node_cnt, nbsum, N_NODES, node_start, node_fill, ndinv);
  hipLaunchKernelGGL(k_fill, dim3((NNZV + 255) / 256), b256, 0, stream,
                     node_idx, edge_idx, edge_start, node_start,
                     edge_fill, node_fill, edge_mem, node_mem);
  hipLaunchKernelGGL(k_encoder, dim3(1024), b256, 0, stream,
                     x, enc_w1, enc_b1, enc_w2, enc_b2, y);
  for (int s = 0; s < STEPS; ++s) {
    hipLaunchKernelGGL(k_edge, dim3(2048), b256, 0, stream,
                       y, e, edge_start, edge_cnt, edge_mem, edinv, conv_w);
    hipLaunchKernelGGL(k_node, dim3(2048), b256, 0, stream,
                       e, y, node_start, node_cnt, node_mem, ndinv,
                       conv_b, sigma, keys, s);
  }
  hipLaunchKernelGGL(k_decoder, dim3(1024), b256, 0, stream,
                     y, dec_w1, dec_b1, dec_w2, dec_b2, (float*)d_out);
}

// Round 14
// 1095.677 us; speedup vs baseline: 1.8424x; 1.0967x over previous
//
#include <hip/hip_runtime.h>
#include <stdint.h>

#define N_NODES 50000
#define N_EDGES 12500
#define NNZV    400000
#define STEPS   20
#define DT_F    0.05f
#define SQRTDT_F 0.22360679774997896f

__device__ __forceinline__ float rdlf(float v, int l) {
  return __uint_as_float(__builtin_amdgcn_readlane(__float_as_uint(v), (unsigned)l));
}
__device__ __forceinline__ int rfl(int v) {
  return (int)__builtin_amdgcn_readfirstlane((unsigned)v);
}

// ---------------- threefry2x32 (partitionable layout) ----------------
__device__ __forceinline__ void tf2x32(uint32_t k0, uint32_t k1,
                                       uint32_t x0, uint32_t x1,
                                       uint32_t& o0, uint32_t& o1) {
  uint32_t k2 = k0 ^ k1 ^ 0x1BD11BDAu;
#define TFR(r) { x0 += x1; x1 = (x1 << (r)) | (x1 >> (32 - (r))); x1 ^= x0; }
  x0 += k0; x1 += k1;
  TFR(13) TFR(15) TFR(26) TFR(6)   x0 += k1; x1 += k2 + 1u;
  TFR(17) TFR(29) TFR(16) TFR(24)  x0 += k2; x1 += k0 + 2u;
  TFR(13) TFR(15) TFR(26) TFR(6)   x0 += k0; x1 += k1 + 3u;
  TFR(17) TFR(29) TFR(16) TFR(24)  x0 += k1; x1 += k2 + 4u;
  TFR(13) TFR(15) TFR(26) TFR(6)   x0 += k2; x1 += k0 + 5u;
#undef TFR
  o0 = x0; o1 = x1;
}

// erfinv, XLA polynomial but with hw log: w = -log((1-u)(1+u))
__device__ __forceinline__ float erfinv_fast(float x) {
  float w = -__logf((1.0f - x) * (1.0f + x));
  float p;
  if (w < 5.0f) {
    w = w - 2.5f;
    p =              2.81022636e-08f;
    p = fmaf(p, w,   3.43273939e-07f);
    p = fmaf(p, w,  -3.5233877e-06f);
    p = fmaf(p, w,  -4.39150654e-06f);
    p = fmaf(p, w,   0.00021858087f);
    p = fmaf(p, w,  -0.00125372503f);
    p = fmaf(p, w,  -0.00417768164f);
    p = fmaf(p, w,   0.246640727f);
    p = fmaf(p, w,   1.50140941f);
  } else {
    w = sqrtf(w) - 3.0f;
    p =             -0.000200214257f;
    p = fmaf(p, w,   0.000100950558f);
    p = fmaf(p, w,   0.00134934322f);
    p = fmaf(p, w,  -0.00367342844f);
    p = fmaf(p, w,   0.00573950773f);
    p = fmaf(p, w,  -0.0076224613f);
    p = fmaf(p, w,   0.00943887047f);
    p = fmaf(p, w,   1.00167406f);
    p = fmaf(p, w,   2.83297682f);
  }
  return p * x;
}

__device__ __forceinline__ float bits_to_normal(uint32_t b) {
  float f = __uint_as_float((b >> 9) | 0x3f800000u) - 1.0f;  // [0,1)
  const float lo = -0.99999994f;
  float u = fmaf(f, 2.0f, lo);
  u = fmaxf(u, lo);
  return 1.41421356237f * erfinv_fast(u);
}

// tanh via hw exp: 1 - 2/(e^{2x}+1)
__device__ __forceinline__ float fast_tanhf(float x) {
  float t = __expf(2.0f * x);
  return 1.0f - 2.0f / (t + 1.0f);
}

// ---------------- setup kernels ----------------
__global__ void k_keys(const int* __restrict__ seed, unsigned* __restrict__ keys) {
  int j = threadIdx.x;
  if (j < STEPS) {
    unsigned s = (unsigned)seed[0];
    unsigned o0, o1;
    tf2x32(0u, s, 0u, (unsigned)j, o0, o1);
    keys[2 * j] = o0; keys[2 * j + 1] = o1;
  }
}

__global__ void k_zero(int* __restrict__ p, int n) {
  int i = blockIdx.x * 256 + threadIdx.x;
  if (i < n) p[i] = 0;
}

__global__ void k_hist(const int* __restrict__ nidx, const int* __restrict__ eidx,
                       int* __restrict__ ecnt, int* __restrict__ ncnt) {
  int i = blockIdx.x * 256 + threadIdx.x;
  if (i < NNZV) {
    atomicAdd(&ecnt[eidx[i]], 1);
    atomicAdd(&ncnt[nidx[i]], 1);
  }
}

// ---- hierarchical exclusive scan over cnt[len]: 1024 elems per block ----
__global__ __launch_bounds__(256) void k_reduce(const int* __restrict__ cnt, int len,
                                                int* __restrict__ bsum) {
  __shared__ int sh[256];
  int b = blockIdx.x, tid = threadIdx.x;
  int base = b * 1024 + tid * 4;
  int s = 0;
#pragma unroll
  for (int j = 0; j < 4; ++j) {
    int i = base + j;
    if (i < len) s += cnt[i];
  }
  sh[tid] = s;
  __syncthreads();
  for (int off = 128; off > 0; off >>= 1) {
    if (tid < off) sh[tid] += sh[tid + off];
    __syncthreads();
  }
  if (tid == 0) bsum[b] = sh[0];
}

__global__ __launch_bounds__(256) void k_scanb(int* __restrict__ bsum, int nb) {
  __shared__ int sh[256];
  int tid = threadIdx.x;
  int v = (tid < nb) ? bsum[tid] : 0;
  sh[tid] = v;
  __syncthreads();
  for (int off = 1; off < 256; off <<= 1) {
    int t = (tid >= off) ? sh[tid - off] : 0;
    __syncthreads();
    sh[tid] += t;
    __syncthreads();
  }
  if (tid < nb) bsum[tid] = sh[tid] - v;   // exclusive
}

__global__ __launch_bounds__(256) void k_scatter(const int* __restrict__ cnt,
                                                 const int* __restrict__ bsum, int len,
                                                 int* __restrict__ start,
                                                 int* __restrict__ fill,
                                                 float* __restrict__ dinv) {
  __shared__ int sh[256];
  int b = blockIdx.x, tid = threadIdx.x;
  int base = b * 1024 + tid * 4;
  int c[4], lex[4];
  int s = 0;
#pragma unroll
  for (int j = 0; j < 4; ++j) {
    int i = base + j;
    c[j] = (i < len) ? cnt[i] : 0;
    lex[j] = s;
    s += c[j];
  }
  sh[tid] = s;
  __syncthreads();
  for (int off = 1; off < 256; off <<= 1) {
    int t = (tid >= off) ? sh[tid - off] : 0;
    __syncthreads();
    sh[tid] += t;
    __syncthreads();
  }
  int off0 = bsum[b] + sh[tid] - s;
#pragma unroll
  for (int j = 0; j < 4; ++j) {
    int i = base + j;
    if (i < len) {
      start[i] = off0 + lex[j];
      fill[i] = 0;
      dinv[i] = 1.0f / (float)(c[j] > 1 ? c[j] : 1);
    }
  }
}

__global__ void k_fill(const int* __restrict__ nidx, const int* __restrict__ eidx,
                       const int* __restrict__ estart, const int* __restrict__ nstart,
                       int* __restrict__ efill, int* __restrict__ nfill,
                       int* __restrict__ emem, int* __restrict__ nmem) {
  int i = blockIdx.x * 256 + threadIdx.x;
  if (i < NNZV) {
    int e = eidx[i], n = nidx[i];
    int pe = atomicAdd(&efill[e], 1);
    emem[estart[e] + pe] = n;
    int pn = atomicAdd(&nfill[n], 1);
    nmem[nstart[n] + pn] = e;
  }
}

// stage a 64x64 row-major matrix into LDS, XOR-swizzled (write & read 2-way = free)
__device__ __forceinline__ void stage_swz(const float* __restrict__ w,
                                          float* __restrict__ lds, int tid) {
  for (int idx = tid; idx < 4096; idx += 256) {
    int j = idx >> 6, k = idx & 63;
    lds[k * 64 + (j ^ k)] = w[idx];
  }
}

// dual-segment scalar gather: TWO independent segments interleaved at 8-row
// granularity -> up to 16 row loads in flight per wave; ids via SGPR loads.
__device__ __forceinline__ void seg_gather_dual(const float* __restrict__ rows,
                                                const int* __restrict__ mem,
                                                int st0, int d0, int st1, int d1,
                                                int lane, float& out0, float& out1) {
  float a0 = 0.f, a1 = 0.f, b0 = 0.f, b1 = 0.f;
  int i0 = 0, i1 = 0;
  while (i0 + 8 <= d0 && i1 + 8 <= d1) {
    int A0 = mem[st0 + i0],     A1 = mem[st0 + i0 + 1];
    int A2 = mem[st0 + i0 + 2], A3 = mem[st0 + i0 + 3];
    int A4 = mem[st0 + i0 + 4], A5 = mem[st0 + i0 + 5];
    int A6 = mem[st0 + i0 + 6], A7 = mem[st0 + i0 + 7];
    int B0 = mem[st1 + i1],     B1 = mem[st1 + i1 + 1];
    int B2 = mem[st1 + i1 + 2], B3 = mem[st1 + i1 + 3];
    int B4 = mem[st1 + i1 + 4], B5 = mem[st1 + i1 + 5];
    int B6 = mem[st1 + i1 + 6], B7 = mem[st1 + i1 + 7];
    float x0 = rows[(size_t)A0 * 64 + lane], x1 = rows[(size_t)A1 * 64 + lane];
    float x2 = rows[(size_t)A2 * 64 + lane], x3 = rows[(size_t)A3 * 64 + lane];
    float x4 = rows[(size_t)A4 * 64 + lane], x5 = rows[(size_t)A5 * 64 + lane];
    float x6 = rows[(size_t)A6 * 64 + lane], x7 = rows[(size_t)A7 * 64 + lane];
    float z0 = rows[(size_t)B0 * 64 + lane], z1 = rows[(size_t)B1 * 64 + lane];
    float z2 = rows[(size_t)B2 * 64 + lane], z3 = rows[(size_t)B3 * 64 + lane];
    float z4 = rows[(size_t)B4 * 64 + lane], z5 = rows[(size_t)B5 * 64 + lane];
    float z6 = rows[(size_t)B6 * 64 + lane], z7 = rows[(size_t)B7 * 64 + lane];
    a0 += (x0 + x1) + (x2 + x3);
    a1 += (x4 + x5) + (x6 + x7);
    b0 += (z0 + z1) + (z2 + z3);
    b1 += (z4 + z5) + (z6 + z7);
    i0 += 8; i1 += 8;
  }
  for (; i0 + 8 <= d0; i0 += 8) {
    int A0 = mem[st0 + i0],     A1 = mem[st0 + i0 + 1];
    int A2 = mem[st0 + i0 + 2], A3 = mem[st0 + i0 + 3];
    int A4 = mem[st0 + i0 + 4], A5 = mem[st0 + i0 + 5];
    int A6 = mem[st0 + i0 + 6], A7 = mem[st0 + i0 + 7];
    float x0 = rows[(size_t)A0 * 64 + lane], x1 = rows[(size_t)A1 * 64 + lane];
    float x2 = rows[(size_t)A2 * 64 + lane], x3 = rows[(size_t)A3 * 64 + lane];
    float x4 = rows[(size_t)A4 * 64 + lane], x5 = rows[(size_t)A5 * 64 + lane];
    float x6 = rows[(size_t)A6 * 64 + lane], x7 = rows[(size_t)A7 * 64 + lane];
    a0 += (x0 + x1) + (x2 + x3);
    a1 += (x4 + x5) + (x6 + x7);
  }
  for (; i0 < d0; ++i0) a0 += rows[(size_t)mem[st0 + i0] * 64 + lane];
  for (; i1 + 8 <= d1; i1 += 8) {
    int B0 = mem[st1 + i1],     B1 = mem[st1 + i1 + 1];
    int B2 = mem[st1 + i1 + 2], B3 = mem[st1 + i1 + 3];
    int B4 = mem[st1 + i1 + 4], B5 = mem[st1 + i1 + 5];
    int B6 = mem[st1 + i1 + 6], B7 = mem[st1 + i1 + 7];
    float z0 = rows[(size_t)B0 * 64 + lane], z1 = rows[(size_t)B1 * 64 + lane];
    float z2 = rows[(size_t)B2 * 64 + lane], z3 = rows[(size_t)B3 * 64 + lane];
    float z4 = rows[(size_t)B4 * 64 + lane], z5 = rows[(size_t)B5 * 64 + lane];
    float z6 = rows[(size_t)B6 * 64 + lane], z7 = rows[(size_t)B7 * 64 + lane];
    b0 += (z0 + z1) + (z2 + z3);
    b1 += (z4 + z5) + (z6 + z7);
  }
  for (; i1 < d1; ++i1) b0 += rows[(size_t)mem[st1 + i1] * 64 + lane];
  out0 = a0 + a1;
  out1 = b0 + b1;
}

// ---------------- encoder: y = relu(x@w1^T+b1)@w2^T + b2 ----------------
__global__ __launch_bounds__(256) void k_encoder(
    const float* __restrict__ x, const float* __restrict__ w1,
    const float* __restrict__ b1, const float* __restrict__ w2,
    const float* __restrict__ b2, float* __restrict__ y) {
  __shared__ float lw1[4096], lw2[4096];
  int tid = threadIdx.x;
  stage_swz(w1, lw1, tid);
  stage_swz(w2, lw2, tid);
  __syncthreads();
  int lane = tid & 63, wave = tid >> 6;
  float w1r[64], w2r[64];
#pragma unroll
  for (int k = 0; k < 64; ++k) {
    w1r[k] = lw1[k * 64 + (lane ^ k)];
    w2r[k] = lw2[k * 64 + (lane ^ k)];
  }
  float b1v = b1[lane], b2v = b2[lane];
  int gw = blockIdx.x * 4 + wave, nw = gridDim.x * 4;
  for (int n = gw; n < N_NODES; n += nw) {
    float xv = x[(size_t)n * 64 + lane];
    float a0 = 0.f, a1 = 0.f, a2 = 0.f, a3 = 0.f;
#pragma unroll
    for (int k = 0; k < 64; k += 4) {
      a0 = fmaf(rdlf(xv, k),     w1r[k],     a0);
      a1 = fmaf(rdlf(xv, k + 1), w1r[k + 1], a1);
      a2 = fmaf(rdlf(xv, k + 2), w1r[k + 2], a2);
      a3 = fmaf(rdlf(xv, k + 3), w1r[k + 3], a3);
    }
    float h = fmaxf((a0 + a1) + (a2 + a3) + b1v, 0.f);
    a0 = a1 = a2 = a3 = 0.f;
#pragma unroll
    for (int k = 0; k < 64; k += 4) {
      a0 = fmaf(rdlf(h, k),     w2r[k],     a0);
      a1 = fmaf(rdlf(h, k + 1), w2r[k + 1], a1);
      a2 = fmaf(rdlf(h, k + 2), w2r[k + 2], a2);
      a3 = fmaf(rdlf(h, k + 3), w2r[k + 3], a3);
    }
    y[(size_t)n * 64 + lane] = (a0 + a1) + (a2 + a3) + b2v;
  }
}

// ---------------- per step: 2 edges/wave, dual scalar gather + shared-weight matvec ----------------
__global__ __launch_bounds__(256) void k_edge(
    const float* __restrict__ y, float* __restrict__ e,
    const int* __restrict__ estart, const int* __restrict__ ecnt,
    const int* __restrict__ emem, const float* __restrict__ edinv,
    const float* __restrict__ cw) {
  __shared__ float lcw[4096];
  int tid = threadIdx.x;
  stage_swz(cw, lcw, tid);
  __syncthreads();
  int lane = tid & 63, wave = tid >> 6;
  const int NE2 = N_EDGES / 2;   // 6250
  int gw = blockIdx.x * 4 + wave, nw = gridDim.x * 4;
  for (int p = gw; p < NE2; p += nw) {
    int p0 = rfl(p);
    int e0 = p0, e1 = p0 + NE2;
    int st0 = estart[e0], d0 = ecnt[e0];
    int st1 = estart[e1], d1 = ecnt[e1];
    float div0 = edinv[e0], div1 = edinv[e1];
    float s0, s1;
    seg_gather_dual(y, emem, st0, d0, st1, d1, lane, s0, s1);
    float a00 = 0.f, a01 = 0.f, a10 = 0.f, a11 = 0.f;
#pragma unroll
    for (int k = 0; k < 64; k += 2) {
      float w0 = lcw[k * 64 + (lane ^ k)];
      float w1 = lcw[(k + 1) * 64 + (lane ^ (k + 1))];
      a00 = fmaf(rdlf(s0, k),     w0, a00);
      a10 = fmaf(rdlf(s1, k),     w0, a10);
      a01 = fmaf(rdlf(s0, k + 1), w1, a01);
      a11 = fmaf(rdlf(s1, k + 1), w1, a11);
    }
    e[(size_t)e0 * 64 + lane] = (a00 + a01) * div0;
    e[(size_t)e1 * 64 + lane] = (a10 + a11) * div1;
  }
}

// ---------------- per step: 2 nodes/wave, dual scalar gather + tanh + noise ----------------
__global__ __launch_bounds__(256) void k_node(
    const float* __restrict__ e, float* __restrict__ y,
    const int* __restrict__ nstart, const int* __restrict__ ncnt,
    const int* __restrict__ nmem, const float* __restrict__ ndinv,
    const float* __restrict__ cb, const float* __restrict__ sigma,
    const unsigned* __restrict__ keys, int s) {
  int tid = threadIdx.x;
  int lane = tid & 63, wave = tid >> 6;
  float cbv = cb[lane];
  float sgv = sigma[lane] * SQRTDT_F;
  unsigned ka = keys[2 * s], kb = keys[2 * s + 1];
  const int NP = N_NODES / 2;    // 25000
  int gw = blockIdx.x * 4 + wave, nw = gridDim.x * 4;
  for (int p = gw; p < NP; p += nw) {
    int p0 = rfl(p);
    int n0 = p0, n1 = p0 + NP;
    int st0 = nstart[n0], d0 = ncnt[n0];
    int st1 = nstart[n1], d1 = ncnt[n1];
    float di0 = ndinv[n0], di1 = ndinv[n1];
    float y0 = y[(size_t)n0 * 64 + lane];    // independent loads, issued early
    float y1 = y[(size_t)n1 * 64 + lane];
    float s0, s1;
    seg_gather_dual(e, nmem, st0, d0, st1, d1, lane, s0, s1);
    uint32_t r0, r1, r2, r3;
    tf2x32(ka, kb, 0u, (unsigned)(n0 * 64 + lane), r0, r1);
    tf2x32(ka, kb, 0u, (unsigned)(n1 * 64 + lane), r2, r3);
    float dw0 = bits_to_normal(r0 ^ r1);
    float dw1 = bits_to_normal(r2 ^ r3);
    y0 = fmaf(fast_tanhf(fmaf(s0, di0, cbv)), DT_F, fmaf(sgv, dw0, y0));
    y1 = fmaf(fast_tanhf(fmaf(s1, di1, cbv)), DT_F, fmaf(sgv, dw1, y1));
    y[(size_t)n0 * 64 + lane] = y0;
    y[(size_t)n1 * 64 + lane] = y1;
  }
}

// ---------------- decoder ----------------
__global__ __launch_bounds__(256) void k_decoder(
    const float* __restrict__ y, const float* __restrict__ w1,
    const float* __restrict__ b1, const float* __restrict__ w2,
    const float* __restrict__ b2, float* __restrict__ out) {
  __shared__ float lw1[4096], lw2[4096];
  int tid = threadIdx.x;
  stage_swz(w1, lw1, tid);
  stage_swz(w2, lw2, tid);
  __syncthreads();
  int lane = tid & 63, wave = tid >> 6;
  float w1r[64], w2r[64];
#pragma unroll
  for (int k = 0; k < 64; ++k) {
    w1r[k] = lw1[k * 64 + (lane ^ k)];
    w2r[k] = lw2[k * 64 + (lane ^ k)];
  }
  float b1v = b1[lane], b2v = b2[lane];
  int gw = blockIdx.x * 4 + wave, nw = gridDim.x * 4;
  for (int n = gw; n < N_NODES; n += nw) {
    float xv = y[(size_t)n * 64 + lane];
    float a0 = 0.f, a1 = 0.f, a2 = 0.f, a3 = 0.f;
#pragma unroll
    for (int k = 0; k < 64; k += 4) {
      a0 = fmaf(rdlf(xv, k),     w1r[k],     a0);
      a1 = fmaf(rdlf(xv, k + 1), w1r[k + 1], a1);
      a2 = fmaf(rdlf(xv, k + 2), w1r[k + 2], a2);
      a3 = fmaf(rdlf(xv, k + 3), w1r[k + 3], a3);
    }
    float h = fmaxf((a0 + a1) + (a2 + a3) + b1v, 0.f);
    a0 = a1 = a2 = a3 = 0.f;
#pragma unroll
    for (int k = 0; k < 64; k += 4) {
      a0 = fmaf(rdlf(h, k),     w2r[k],     a0);
      a1 = fmaf(rdlf(h, k + 1), w2r[k + 1], a1);
      a2 = fmaf(rdlf(h, k + 2), w2r[k + 2], a2);
      a3 = fmaf(rdlf(h, k + 3), w2r[k + 3], a3);
    }
    out[(size_t)n * 64 + lane] = (a0 + a1) + (a2 + a3) + b2v;
  }
}

extern "C" void kernel_launch(void* const* d_in, const int* in_sizes, int n_in,
                              void* d_out, int out_size, void* d_ws, size_t ws_size,
                              hipStream_t stream) {
  (void)in_sizes; (void)n_in; (void)out_size; (void)ws_size;
  const float* x      = (const float*)d_in[0];
  const float* enc_w1 = (const float*)d_in[1];
  const float* enc_b1 = (const float*)d_in[2];
  const float* enc_w2 = (const float*)d_in[3];
  const float* enc_b2 = (const float*)d_in[4];
  const float* conv_w = (const float*)d_in[5];
  const float* conv_b = (const float*)d_in[6];
  const float* sigma  = (const float*)d_in[7];
  const float* dec_w1 = (const float*)d_in[8];
  const float* dec_b1 = (const float*)d_in[9];
  const float* dec_w2 = (const float*)d_in[10];
  const float* dec_b2 = (const float*)d_in[11];
  const int* node_idx = (const int*)d_in[12];
  const int* edge_idx = (const int*)d_in[13];
  const int* seed     = (const int*)d_in[14];

  char* wsb = (char*)d_ws;
  size_t off = 0;
  auto alloc = [&](size_t bytes) -> void* {
    void* p = wsb + off;
    off = (off + bytes + 255) & ~(size_t)255;
    return p;
  };
  float* y        = (float*)alloc((size_t)N_NODES * 64 * 4);
  float* e        = (float*)alloc((size_t)N_EDGES * 64 * 4);
  int* edge_cnt   = (int*)alloc((size_t)N_EDGES * 4);
  int* node_cnt   = (int*)alloc((size_t)N_NODES * 4);
  int* edge_start = (int*)alloc((size_t)N_EDGES * 4);
  int* node_start = (int*)alloc((size_t)N_NODES * 4);
  int* edge_fill  = (int*)alloc((size_t)N_EDGES * 4);
  int* node_fill  = (int*)alloc((size_t)N_NODES * 4);
  int* edge_mem   = (int*)alloc((size_t)NNZV * 4);
  int* node_mem   = (int*)alloc((size_t)NNZV * 4);
  float* edinv    = (float*)alloc((size_t)N_EDGES * 4);
  float* ndinv    = (float*)alloc((size_t)N_NODES * 4);
  unsigned* keys  = (unsigned*)alloc(2 * STEPS * 4);
  int* ebsum      = (int*)alloc(256 * 4);
  int* nbsum      = (int*)alloc(256 * 4);

  const int EB = (N_EDGES + 1023) / 1024;   // 13
  const int NB = (N_NODES + 1023) / 1024;   // 49

  dim3 b256(256);
  hipLaunchKernelGGL(k_keys, dim3(1), dim3(64), 0, stream, seed, keys);
  hipLaunchKernelGGL(k_zero, dim3((N_EDGES + 255) / 256), b256, 0, stream, edge_cnt, N_EDGES);
  hipLaunchKernelGGL(k_zero, dim3((N_NODES + 255) / 256), b256, 0, stream, node_cnt, N_NODES);
  hipLaunchKernelGGL(k_hist, dim3((NNZV + 255) / 256), b256, 0, stream,
                     node_idx, edge_idx, edge_cnt, node_cnt);
  hipLaunchKernelGGL(k_reduce, dim3(EB), b256, 0, stream, edge_cnt, N_EDGES, ebsum);
  hipLaunchKernelGGL(k_reduce, dim3(NB), b256, 0, stream, node_cnt, N_NODES, nbsum);
  hipLaunchKernelGGL(k_scanb, dim3(1), b256, 0, stream, ebsum, EB);
  hipLaunchKernelGGL(k_scanb, dim3(1), b256, 0, stream, nbsum, NB);
  hipLaunchKernelGGL(k_scatter, dim3(EB), b256, 0, stream,
                     edge_cnt, ebsum, N_EDGES, edge_start, edge_fill, edinv);
  hipLaunchKernelGGL(k_scatter, dim3(NB), b256, 0, stream,
                     node_cnt, nbsum, N_NODES, node_start, node_fill, ndinv);
  hipLaunchKernelGGL(k_fill, dim3((NNZV + 255) / 256), b256, 0, stream,
                     node_idx, edge_idx, edge_start, node_start,
                     edge_fill, node_fill, edge_mem, node_mem);
  hipLaunchKernelGGL(k_encoder, dim3(1024), b256, 0, stream,
                     x, enc_w1, enc_b1, enc_w2, enc_b2, y);
  for (int s = 0; s < STEPS; ++s) {
    hipLaunchKernelGGL(k_edge, dim3(1563), b256, 0, stream,
                       y, e, edge_start, edge_cnt, edge_mem, edinv, conv_w);
    hipLaunchKernelGGL(k_node, dim3(2048), b256, 0, stream,
                       e, y, node_start, node_cnt, node_mem, ndinv,
                       conv_b, sigma, keys, s);
  }
  hipLaunchKernelGGL(k_decoder, dim3(1024), b256, 0, stream,
                     y, dec_w1, dec_b1, dec_w2, dec_b2, (float*)d_out);
}